// Round 2
// baseline (122.092 us; speedup 1.0000x reference)
//
#include <hip/hip_runtime.h>

// Local NCC loss on (2,1,160,160,160) f32 volumes, 5x5x5 box window, SAME zero pad.
// Barrier-free wave-autonomous design:
//   wave = 4 output h-rows x 32 output w-cols, loops over TD=16 depth slabs (+4 halo).
//   pass2: H-direction 5-sums of {I,J,I2,J2,IJ} read directly from global (L1-cached
//          aligned float4 quads, static per-lane voffsets), written b128 to wave-private LDS.
//   pass3: W-direction window sums from b64 LDS reads; per-lane D-ring (5 deep, static
//          slots via 5x unroll) with running z-sums; cc evaluated per output, accumulated.
//   No __syncthreads at all; intra-wave LDS ordering via wave_barrier.

#define DIM 160
#define SLAB (DIM * DIM)          // 25600
#define VOL (DIM * DIM * DIM)     // 4096000
#define TD 16
#define NPART 4000                // 1000 blocks * 4 waves

typedef float f4 __attribute__((ext_vector_type(4), aligned(16)));
typedef float f2 __attribute__((ext_vector_type(2), aligned(8)));

__global__ __launch_bounds__(256, 4) void ncc_main(const float* __restrict__ real,
                                                   const float* __restrict__ fake,
                                                   float* __restrict__ partials) {
    // wave-private H-sum staging: [wave][quantity][row][x], x covers w0-4 .. w0+35
    __shared__ float hs[4][5][4][40];

    const int lane = threadIdx.x;   // 0..63
    const int wid  = threadIdx.y;   // 0..3
    const int bx = blockIdx.x, by = blockIdx.y, bz = blockIdx.z;
    const int w0 = bx * 32;
    const int hw = by * 16 + wid * 4;       // wave's first output row
    const int n  = bz / 10;
    const int d0 = (bz % 10) * TD;

    // pass3 mapping: ty = output row (0..3), tx owns outputs w0+2tx, w0+2tx+1
    const int ty = lane >> 4;
    const int tx = lane & 15;

    // pass2 mapping: 40 active lanes, (i2 = hs row 0..3, u2 = quad 0..9)
    const int i2 = lane / 10;
    const int u2 = lane - 10 * i2;
    const bool p2act = lane < 40;

    const int wq = w0 - 4 + 4 * u2;         // aligned quad start (may be -4)

    // per-r (kernel row) precompute: clamped voffsets + row-valid multipliers
    int   voff[5];
    float hokf[5];
#pragma unroll
    for (int r = 0; r < 5; ++r) {
        const int h  = hw + i2 - 2 + r;
        const int hc = min(max(h, 0), DIM - 1);
        int a = hc * DIM + wq;
        a = min(max(a, 0), SLAB - 4);
        voff[r] = a;
        hokf[r] = (h >= 0 && h < DIM) ? 1.f : 0.f;
    }
    // per-component w-valid multipliers (lane-constant)
    float wmf[4];
#pragma unroll
    for (int j = 0; j < 4; ++j)
        wmf[j] = ((unsigned)(wq + j) < (unsigned)DIM) ? 1.f : 0.f;

    const bool wedge = (bx == 0) | (bx == 4);
    const bool hedge = (by == 0) | (by == 9);

    const float* baseI = real + (size_t)n * VOL;
    const float* baseJ = fake + (size_t)n * VOL;

    float ring[5][2][5];   // [quantity][output][slot]
    float zs[5][2];
#pragma unroll
    for (int q = 0; q < 5; ++q)
#pragma unroll
        for (int o = 0; o < 2; ++o) {
            zs[q][o] = 0.f;
#pragma unroll
            for (int t = 0; t < 5; ++t) ring[q][o][t] = 0.f;
        }

    float acc = 0.f;
    const float inv = 1.0f / 125.0f;

    for (int a5 = 0; a5 < 4; ++a5) {
#pragma unroll
        for (int b5 = 0; b5 < 5; ++b5) {
            const int s  = a5 * 5 + b5;          // slab index 0..19
            const int dd = d0 - 2 + s;
            const bool dok = (dd >= 0) & (dd < DIM);

            // ---- pass2: H-direction 5-sums -> wave-private LDS ----
            if (p2act) {
                if (dok) {
                    const float* pI = baseI + (size_t)dd * SLAB;
                    const float* pJ = baseJ + (size_t)dd * SLAB;
                    float sA[4]  = {0, 0, 0, 0}, sB[4]  = {0, 0, 0, 0};
                    float sA2[4] = {0, 0, 0, 0}, sB2[4] = {0, 0, 0, 0};
                    float sAB[4] = {0, 0, 0, 0};
#pragma unroll
                    for (int r = 0; r < 5; ++r) {
                        f4 vI = *(const f4*)(pI + voff[r]);
                        f4 vJ = *(const f4*)(pJ + voff[r]);
                        if (wedge) {   // zero w-OOB components (edge quads only)
                            vI.x *= wmf[0]; vI.y *= wmf[1]; vI.z *= wmf[2]; vI.w *= wmf[3];
                            vJ.x *= wmf[0]; vJ.y *= wmf[1]; vJ.z *= wmf[2]; vJ.w *= wmf[3];
                        }
                        if (hedge) {   // zero h-OOB rows
                            const float m = hokf[r];
                            vI.x *= m; vI.y *= m; vI.z *= m; vI.w *= m;
                            vJ.x *= m; vJ.y *= m; vJ.z *= m; vJ.w *= m;
                        }
                        sA[0] += vI.x; sA[1] += vI.y; sA[2] += vI.z; sA[3] += vI.w;
                        sB[0] += vJ.x; sB[1] += vJ.y; sB[2] += vJ.z; sB[3] += vJ.w;
                        sA2[0] = fmaf(vI.x, vI.x, sA2[0]); sA2[1] = fmaf(vI.y, vI.y, sA2[1]);
                        sA2[2] = fmaf(vI.z, vI.z, sA2[2]); sA2[3] = fmaf(vI.w, vI.w, sA2[3]);
                        sB2[0] = fmaf(vJ.x, vJ.x, sB2[0]); sB2[1] = fmaf(vJ.y, vJ.y, sB2[1]);
                        sB2[2] = fmaf(vJ.z, vJ.z, sB2[2]); sB2[3] = fmaf(vJ.w, vJ.w, sB2[3]);
                        sAB[0] = fmaf(vI.x, vJ.x, sAB[0]); sAB[1] = fmaf(vI.y, vJ.y, sAB[1]);
                        sAB[2] = fmaf(vI.z, vJ.z, sAB[2]); sAB[3] = fmaf(vI.w, vJ.w, sAB[3]);
                    }
                    *(f4*)&hs[wid][0][i2][4 * u2] = (f4){sA[0],  sA[1],  sA[2],  sA[3]};
                    *(f4*)&hs[wid][1][i2][4 * u2] = (f4){sB[0],  sB[1],  sB[2],  sB[3]};
                    *(f4*)&hs[wid][2][i2][4 * u2] = (f4){sA2[0], sA2[1], sA2[2], sA2[3]};
                    *(f4*)&hs[wid][3][i2][4 * u2] = (f4){sB2[0], sB2[1], sB2[2], sB2[3]};
                    *(f4*)&hs[wid][4][i2][4 * u2] = (f4){sAB[0], sAB[1], sAB[2], sAB[3]};
                } else {
                    const f4 z = (f4){0.f, 0.f, 0.f, 0.f};
#pragma unroll
                    for (int q = 0; q < 5; ++q)
                        *(f4*)&hs[wid][q][i2][4 * u2] = z;
                }
            }

            __builtin_amdgcn_wave_barrier();   // order pass2 writes before pass3 reads

            // ---- pass3: W-window sums + D-ring running z-sums ----
#pragma unroll
            for (int q = 0; q < 5; ++q) {
                const f2 f0 = *(const f2*)&hs[wid][q][ty][2 * tx + 2];
                const f2 f1 = *(const f2*)&hs[wid][q][ty][2 * tx + 4];
                const f2 f2v = *(const f2*)&hs[wid][q][ty][2 * tx + 6];
                const float s0 = f0.x + f0.y + f1.x + f1.y + f2v.x;
                const float s1 = s0 - f0.x + f2v.y;
                zs[q][0] += s0 - ring[q][0][b5]; ring[q][0][b5] = s0;
                zs[q][1] += s1 - ring[q][1][b5]; ring[q][1][b5] = s1;
            }

            __builtin_amdgcn_wave_barrier();   // order pass3 reads before next pass2 writes

            if (s >= 4) {
#pragma unroll
                for (int o = 0; o < 2; ++o) {
                    const float t0    = zs[0][o] * inv;
                    const float cross = fmaf(-t0, zs[1][o], zs[4][o]);
                    const float iv    = fmaf(-t0, zs[0][o], zs[2][o]);
                    const float jv    = fmaf(-(zs[1][o] * inv), zs[1][o], zs[3][o]);
                    acc += cross * cross / (fmaf(iv, jv, 1e-5f));
                }
            }
        }
    }

    // wave reduction -> one partial per wave
#pragma unroll
    for (int off = 32; off; off >>= 1)
        acc += __shfl_down(acc, off, 64);
    if (lane == 0) {
        const int gb = (bz * gridDim.y + by) * gridDim.x + bx;
        partials[gb * 4 + wid] = acc;
    }
}

__global__ void ncc_reduce(const float* __restrict__ partials, float* __restrict__ out) {
    __shared__ double ws[4];
    double s = 0.0;
    for (int i = threadIdx.x; i < NPART; i += 256) s += (double)partials[i];
#pragma unroll
    for (int off = 32; off; off >>= 1)
        s += __shfl_down(s, off, 64);
    if ((threadIdx.x & 63) == 0) ws[threadIdx.x >> 6] = s;
    __syncthreads();
    if (threadIdx.x == 0) {
        const double t = ws[0] + ws[1] + ws[2] + ws[3];
        out[0] = (float)(t / (2.0 * (double)VOL));
    }
}

extern "C" void kernel_launch(void* const* d_in, const int* in_sizes, int n_in,
                              void* d_out, int out_size, void* d_ws, size_t ws_size,
                              hipStream_t stream) {
    const float* real = (const float*)d_in[0];
    const float* fake = (const float*)d_in[1];
    float* out      = (float*)d_out;
    float* partials = (float*)d_ws;   // NPART floats

    dim3 grid(5, 10, 20);             // (w tiles, h tiles, 2 batches * 10 d-chunks)
    dim3 block(64, 4, 1);             // 4 waves
    ncc_main<<<grid, block, 0, stream>>>(real, fake, partials);
    ncc_reduce<<<1, 256, 0, stream>>>(partials, out);
}

// Round 3
// 112.629 us; speedup vs baseline: 1.0840x; 1.0840x over previous
//
#include <hip/hip_runtime.h>

// Local NCC loss on (2,1,160,160,160) f32, 5x5x5 box window, SAME zero pad.
// Block = 256 thr (4 waves), output tile 32h x 32w x 16d.
// Per slab: raw I/J staged once in LDS (zero-padded, double-buffered);
// each lane computes vertical 5-sums of {I,J,I2,J2,IJ} for 8 x-positions from
// b128 LDS reads, horizontal sliding 5-sums for its 4 outputs, and feeds 5
// rotating D-phase accumulators (registers, statically indexed). A phase
// completes every 5 slabs -> evaluate cc, accumulate, reset.

#define DIM 160
#define SLAB (DIM * DIM)          // 25600
#define VOL (DIM * DIM * DIM)     // 4096000
#define TD 16
#define NBLK 500                  // 5 x 5 x 20
#define NPART (NBLK * 4)

typedef float f4 __attribute__((ext_vector_type(4), aligned(16)));

__device__ inline f4 hwin(const f4 lo, const f4 hi) {
    // 5-wide sliding window sums over the 8 values [lo.xyzw, hi.xyzw]
    const float c0 = lo.x + lo.y + lo.z + lo.w + hi.x;
    const float c1 = c0 - lo.x + hi.y;
    const float c2 = c1 - lo.y + hi.z;
    const float c3 = c2 - lo.z + hi.w;
    return (f4){c0, c1, c2, c3};
}

__global__ __launch_bounds__(256, 2) void ncc_main(const float* __restrict__ real,
                                                   const float* __restrict__ fake,
                                                   float* __restrict__ partials) {
    __shared__ float lds[2][2][36][40];   // [buf][vol][row][x] : x=i <-> w = w0-2+i

    const int tid  = threadIdx.x;
    const int lane = tid & 63;
    const int wid  = tid >> 6;
    const int bx = blockIdx.x, by = blockIdx.y, bz = blockIdx.z;
    const int w0 = bx * 32, h0 = by * 32;
    const int n  = bz / 10;
    const int d0 = (bz % 10) * TD;

    // compute mapping: lane = r*8 + c; output row y = wid*8 + r; w strip = w0 + 4c
    const int rr0  = lane >> 3;          // 0..7
    const int cc0  = lane & 7;           // 0..7
    const int yrow = wid * 8 + rr0;      // 0..31 ; window = staged rows yrow..yrow+4
    const int xoff = 4 * cc0;            // f4 reads at xoff and xoff+4

    // staging mapping: waves 0,1 -> real ; waves 2,3 -> fake (wave-uniform ptr)
    const int hv = tid >> 7;
    const int st = tid & 127;
    const float* sp = (hv ? fake : real) + (size_t)n * VOL;

    int   g[12];
    float okf[12];
#pragma unroll
    for (int k = 0; k < 12; ++k) {
        const int e = st + 128 * k;          // 0..1535 (>=1440 inactive)
        const int r = e / 40, i = e % 40;
        const int hr = h0 - 2 + r;
        const int w  = w0 - 2 + i;
        const bool ok = ((unsigned)hr < DIM) && ((unsigned)w < DIM) && (e < 1440);
        int gg = hr * DIM + w;
        gg = min(max(gg, 0), SLAB - 1);      // clamped: loads stay in-bounds
        g[k]   = gg;
        okf[k] = ok ? 1.f : 0.f;
    }

    const float inv = 1.0f / 125.0f;
    const f4 zf = (f4){0.f, 0.f, 0.f, 0.f};

    f4 zs[5][5];                             // [phase][quantity] x 4 outputs
#pragma unroll
    for (int p = 0; p < 5; ++p)
#pragma unroll
        for (int q = 0; q < 5; ++q) zs[p][q] = zf;

    // ---- prologue: stage slab dd = d0-2 into buf 0 ----
    {
        const int dd = d0 - 2;
        float v[12];
        if ((unsigned)dd < DIM) {
            const float* ps = sp + (size_t)dd * SLAB;
#pragma unroll
            for (int k = 0; k < 12; ++k) v[k] = okf[k] * ps[g[k]];
        } else {
#pragma unroll
            for (int k = 0; k < 12; ++k) v[k] = 0.f;
        }
        float* wp = &lds[0][hv][0][0];
#pragma unroll
        for (int k = 0; k < 12; ++k)
            if (k < 11 || st < 32) wp[st + 128 * k] = v[k];
    }
    __syncthreads();

    float acc = 0.f;
    int cur = 0;

    for (int a5 = 0; a5 < 4; ++a5) {
        const bool am0 = (a5 > 0);
        const bool am3 = (a5 < 3);
#pragma unroll
        for (int b5 = 0; b5 < 5; ++b5) {
            const int dd = d0 - 2 + 5 * a5 + b5;

            // ---- issue next-slab global loads (held in regs) ----
            float v[12];
            const bool haveNext = (b5 < 4) || am3;
            if (haveNext) {
                const int dd1 = dd + 1;
                if ((unsigned)dd1 < DIM) {
                    const float* ps = sp + (size_t)dd1 * SLAB;
#pragma unroll
                    for (int k = 0; k < 12; ++k) v[k] = okf[k] * ps[g[k]];
                } else {
#pragma unroll
                    for (int k = 0; k < 12; ++k) v[k] = 0.f;
                }
            }

            // ---- compute this slab's 5 quantities' 5x5 window sums ----
            const float* LI = &lds[cur][0][0][0];
            const float* LJ = &lds[cur][1][0][0];
            f4 vI0 = zf, vI1 = zf, vJ0 = zf, vJ1 = zf;
            f4 vI20 = zf, vI21 = zf, vJ20 = zf, vJ21 = zf, vIJ0 = zf, vIJ1 = zf;
#pragma unroll
            for (int t = 0; t < 5; ++t) {
                const int ro = (yrow + t) * 40 + xoff;
                const f4 a0 = *(const f4*)(LI + ro);
                const f4 a1 = *(const f4*)(LI + ro + 4);
                const f4 b0 = *(const f4*)(LJ + ro);
                const f4 b1 = *(const f4*)(LJ + ro + 4);
                vI0 += a0; vI1 += a1; vJ0 += b0; vJ1 += b1;
                vI20 += a0 * a0; vI21 += a1 * a1;
                vJ20 += b0 * b0; vJ21 += b1 * b1;
                vIJ0 += a0 * b0; vIJ1 += a1 * b1;
            }
            const f4 csI  = hwin(vI0, vI1);
            const f4 csJ  = hwin(vJ0, vJ1);
            const f4 csI2 = hwin(vI20, vI21);
            const f4 csJ2 = hwin(vJ20, vJ21);
            const f4 csIJ = hwin(vIJ0, vIJ1);

            // ---- add to active D-phases (compile-time case per (b5,p)) ----
#pragma unroll
            for (int p = 0; p < 5; ++p) {
                const int kk = (b5 - p + 5) % 5;   // window age of phase p
                bool doadd;
                if (kk == b5)      doadd = true;   // always-valid phase
                else if (kk > b5)  doadd = am0;    // window started in prev a5-group
                else               doadd = am3;    // window extends past t=15 at a5==3
                if (doadd) {
                    zs[p][0] += csI;  zs[p][1] += csJ;
                    zs[p][2] += csI2; zs[p][3] += csJ2; zs[p][4] += csIJ;
                }
            }

            // ---- completed phase (s >= 4): evaluate cc for 4 outputs ----
            if (am0 || b5 == 4) {
                const int pe = (b5 + 1) % 5;
                const f4 SI = zs[pe][0], SJ = zs[pe][1];
                const f4 S2I = zs[pe][2], S2J = zs[pe][3], SIJ = zs[pe][4];
                const f4 cross = SIJ - SI * SJ * inv;
                const f4 iv    = S2I - SI * SI * inv;
                const f4 jv    = S2J - SJ * SJ * inv;
                const f4 cc    = cross * cross / (iv * jv + 1e-5f);
                acc += cc.x + cc.y + cc.z + cc.w;
                zs[pe][0] = zf; zs[pe][1] = zf; zs[pe][2] = zf;
                zs[pe][3] = zf; zs[pe][4] = zf;
            }

            // ---- write staged regs -> other buffer, flip ----
            if (haveNext) {
                float* wp = &lds[cur ^ 1][hv][0][0];
#pragma unroll
                for (int k = 0; k < 12; ++k)
                    if (k < 11 || st < 32) wp[st + 128 * k] = v[k];
            }
            __syncthreads();
            cur ^= 1;
        }
    }

    // ---- wave reduction -> one partial per wave ----
#pragma unroll
    for (int off = 32; off; off >>= 1)
        acc += __shfl_down(acc, off, 64);
    if (lane == 0) {
        const int blin = (bz * gridDim.y + by) * gridDim.x + bx;
        partials[blin * 4 + wid] = acc;
    }
}

__global__ void ncc_reduce(const float* __restrict__ partials, float* __restrict__ out) {
    __shared__ double ws[4];
    double s = 0.0;
    for (int i = threadIdx.x; i < NPART; i += 256) s += (double)partials[i];
#pragma unroll
    for (int off = 32; off; off >>= 1)
        s += __shfl_down(s, off, 64);
    if ((threadIdx.x & 63) == 0) ws[threadIdx.x >> 6] = s;
    __syncthreads();
    if (threadIdx.x == 0) {
        const double t = ws[0] + ws[1] + ws[2] + ws[3];
        out[0] = (float)(t / (2.0 * (double)VOL));
    }
}

extern "C" void kernel_launch(void* const* d_in, const int* in_sizes, int n_in,
                              void* d_out, int out_size, void* d_ws, size_t ws_size,
                              hipStream_t stream) {
    const float* real = (const float*)d_in[0];
    const float* fake = (const float*)d_in[1];
    float* out      = (float*)d_out;
    float* partials = (float*)d_ws;   // NPART floats

    dim3 grid(5, 5, 20);              // (w tiles, h tiles, 2 batches * 10 d-chunks)
    dim3 block(256, 1, 1);
    ncc_main<<<grid, block, 0, stream>>>(real, fake, partials);
    ncc_reduce<<<1, 256, 0, stream>>>(partials, out);
}